// Round 7
// baseline (85.400 us; speedup 1.0000x reference)
//
#include <hip/hip_runtime.h>

// ReflectionRayTracer: 8192 rays x 2048 quad surfaces. out[ray][surf] = t*mask.
//
// R7: test the untested cell of the A/B matrix — wider, more-local stores at
// FULL occupancy. (R4 = wide stores but 1/2..1/4 occupancy: lost. R6 = full
// occupancy but 256B/wave scalar-store stream jumping 8KB/iter: 22.6 us,
// VALU ~38% / write-BW ~47% -> latency/locality regime, nothing saturated.)
//  - SPT=2: thread owns surfaces (2t, 2t+1) -> one float2 (dwordx2) store per
//    ray, 512 B/wave-instr; store count and loop overhead halved; ray loads
//    amortized over 2 pairs.
//  - Coeff cost: 2 x 13 = 26 VGPRs + ~20 working — fits 64 VGPR, so
//    __launch_bounds__(256,8) keeps 8 waves/SIMD (R4's failure was VGPR-driven
//    occupancy loss, not width).
//  - Block footprint 512 cols x 16 rows: per-iteration the block writes 2 KB
//    contiguous; each 8-KB output row is split across 4 blocks (was 8).
//    Grid (4, 512) = 2048 blocks = 8 blocks/CU.
// Per-pair math is UNCHANGED from R6 -> output bit-identical, absmax must be
// exactly 2.578125 (correctness check for the regrouping).

#define N_RAYS 8192
#define N_SURF 2048
constexpr int SPT = 2;    // surfaces per thread
constexpr int RPB = 16;   // rays (rows) per block

__device__ __forceinline__ float safef(float x) {
    return (x == 0.0f) ? 1e-18f : x;   // jnp.where(x==0, EPS, x)
}

struct Coeffs {
    float vx, vy, vz, k;          // plane
    float g0, g1, g2;             // gam  = g  . r
    float bb0, bb1, bb2;          // beta = bb . r
    float aa0, aa1, aa2;          // alpha= aa . r
};

__device__ __forceinline__ Coeffs surface_coeffs(const float* __restrict__ V, int s)
{
    const float4 p0 = *(const float4*)(V + (size_t)s * 12);
    const float4 p1 = *(const float4*)(V + (size_t)s * 12 + 4);
    const float4 p2 = *(const float4*)(V + (size_t)s * 12 + 8);
    const float ax = p0.x, ay = p0.y, az = p0.z;       // a = V[s][0]
    const float bx = p0.w, by = p1.x, bz = p1.y;       // b = V[s][1]
    const float cx = p1.z, cy = p1.w, cz = p2.x;       // c = V[s][2]
    const float wx = p2.y, wy = p2.z, wz = p2.w;       // V[s][3]

    // Plane: v = normalize(cross(b-a, c-a)); k = -dot(v, V[s][3])
    const float e0x = bx - ax, e0y = by - ay, e0z = bz - az;
    const float e1x = cx - ax, e1y = cy - ay, e1z = cz - az;
    const float nx = e0y * e1z - e0z * e1y;
    const float ny = e0z * e1x - e0x * e1z;
    const float nz = e0x * e1y - e0y * e1x;
    const float rn = __builtin_amdgcn_rsqf(fmaf(nx, nx, fmaf(ny, ny, nz * nz)));
    const float vx = nx * rn, vy = ny * rn, vz = nz * rn;
    const float k = -fmaf(vx, wx, fmaf(vy, wy, vz * wz));

    // Reference constants:
    const float B  = ax * bz - az * bx;
    const float D  = ax * by - ay * bx;                 // G == D
    const float E  = ax * cz - az * cx;
    const float P  = ay * cx - ax * cy;
    const float F  = B * P;
    const float rden = __builtin_amdgcn_rcpf(safef(D * fmaf(E, D, F)));
    const float rD   = __builtin_amdgcn_rcpf(safef(D));
    const float rAX  = __builtin_amdgcn_rcpf(safef(ax));

    Coeffs c;
    c.vx = vx; c.vy = vy; c.vz = vz; c.k = k;
    const float DB = D * B, DD = D * D;
    c.g0 = (DB * ay - DD * az) * rden;
    c.g1 = -(DB * ax) * rden;
    c.g2 = (DD * ax) * rden;
    const float bp = P * rD;
    c.bb0 = fmaf(bp, c.g0, -ay * rD);
    c.bb1 = fmaf(bp, c.g1,  ax * rD);
    c.bb2 = bp * c.g2;
    const float ab = -bx * rAX, ac = -cx * rAX;
    c.aa0 = fmaf(ab, c.bb0, fmaf(ac, c.g0, rAX));
    c.aa1 = fmaf(ab, c.bb1, ac * c.g1);
    c.aa2 = fmaf(ab, c.bb2, ac * c.g2);
    return c;
}

__device__ __forceinline__ float trace_pair(
    const Coeffs& c, float o0, float o1, float o2, float d0, float d1, float d2)
{
    const float vo_k = fmaf(o0, c.vx, fmaf(o1, c.vy, fmaf(o2, c.vz, c.k)));  // k + v.o
    const float vd   = fmaf(d0, c.vx, fmaf(d1, c.vy, d2 * c.vz));
    const float t    = -vo_k * __builtin_amdgcn_rcpf(vd);

    const float rx = fmaf(t, d0, o0);
    const float ry = fmaf(t, d1, o1);
    const float rz = fmaf(t, d2, o2);

    const float gam   = fmaf(c.g0,  rx, fmaf(c.g1,  ry, c.g2  * rz));
    const float beta  = fmaf(c.bb0, rx, fmaf(c.bb1, ry, c.bb2 * rz));
    const float alpha = fmaf(c.aa0, rx, fmaf(c.aa1, ry, c.aa2 * rz));

    const float mn = fminf(fminf(beta, gam), alpha);   // v_min3_f32
    return (mn > 0.0f) ? t : 0.0f;
}

__global__ __launch_bounds__(256, 8) void trace_kernel(
    const float* __restrict__ o, const float* __restrict__ dr,
    const float* __restrict__ V, float* __restrict__ out)
{
    const int s0 = (blockIdx.x * 256 + threadIdx.x) * SPT;  // 2 consecutive surfaces

    const Coeffs ca = surface_coeffs(V, s0);
    const Coeffs cb = surface_coeffs(V, s0 + 1);

    const int ray0 = blockIdx.y * RPB;
    float* outp = out + (size_t)ray0 * N_SURF + s0;
#pragma unroll 4
    for (int i = 0; i < RPB; ++i) {
        const int ray = ray0 + i;
        // Block-uniform ray loads -> scalar loads.
        const float o0 = o[ray * 3 + 0], o1 = o[ray * 3 + 1], o2 = o[ray * 3 + 2];
        const float d0 = dr[ray * 3 + 0], d1 = dr[ray * 3 + 1], d2 = dr[ray * 3 + 2];

        float2 res;
        res.x = trace_pair(ca, o0, o1, o2, d0, d1, d2);
        res.y = trace_pair(cb, o0, o1, o2, d0, d1, d2);
        *(float2*)(outp + (size_t)i * N_SURF) = res;   // 8B-aligned (s0 even), dwordx2
    }
}

extern "C" void kernel_launch(void* const* d_in, const int* in_sizes, int n_in,
                              void* d_out, int out_size, void* d_ws, size_t ws_size,
                              hipStream_t stream) {
    const float* o  = (const float*)d_in[0];
    const float* dr = (const float*)d_in[1];
    const float* V  = (const float*)d_in[2];
    float* out = (float*)d_out;

    trace_kernel<<<dim3(N_SURF / (256 * SPT), N_RAYS / RPB), dim3(256), 0, stream>>>(o, dr, V, out);
}